// Round 1
// baseline (475.277 us; speedup 1.0000x reference)
//
#include <hip/hip_runtime.h>
#include <hip/hip_bf16.h>

#define B_   32
#define N_   2048
#define VD_  512
#define AD_  128
#define SD_  128
#define HD_  64
#define TM   64      // tokens per block
#define KC   32      // K chunk staged in LDS

__device__ __forceinline__ float sigmoidf_(float x) {
    return 1.0f / (1.0f + expf(-x));
}

// Fused per-token pipeline. Grid: 32 b * 32 tiles = 1024 blocks, 256 threads.
// Thread (ty,tx): ty=tid>>4 owns token rows ty*4..ty*4+3; tx=tid&15 owns cols.
__global__ __launch_bounds__(256, 2)
void fused_mil(const float* __restrict__ vfeat, const float* __restrict__ afeat,
               const float* __restrict__ vfc_w, const float* __restrict__ vfc_b,
               const float* __restrict__ afc_w, const float* __restrict__ afc_b,
               const float* __restrict__ am_w,  const float* __restrict__ am_b,
               const float* __restrict__ U_w,   const float* __restrict__ U_b,
               const float* __restrict__ V_w,   const float* __restrict__ V_b,
               const float* __restrict__ W_w,   const float* __restrict__ W_b,
               float* __restrict__ s_out, float* __restrict__ zpart)
{
    __shared__ float sA[TM][36];    // token x Kchunk (pad 36: 16B-aligned rows)
    __shared__ float sW[128][36];   // out-col x Kchunk
    __shared__ float sF[TM][132];   // ax, later ffeat
    __shared__ float sS[TM];        // per-token score

    const int tid  = threadIdx.x;
    const int bx   = blockIdx.x;
    const int b    = bx >> 5;
    const int tile = bx & 31;
    const int tok0 = tile * TM;
    const int ty = tid >> 4;
    const int tx = tid & 15;
    const int r0 = ty * 4;
    const int c0 = tx * 8;

    float acc[4][8];
    float gate[4][8];

    // ---------------- Phase A: ax = relu(afeat @ afc_w^T + afc_b) ----------------
    #pragma unroll
    for (int i = 0; i < 4; ++i)
        #pragma unroll
        for (int j = 0; j < 8; ++j) acc[i][j] = 0.0f;

    for (int k0 = 0; k0 < AD_; k0 += KC) {
        for (int idx = tid; idx < TM * 8; idx += 256) {
            int r = idx >> 3, kq = idx & 7;
            float4 v = ((const float4*)afeat)[(size_t)(b * N_ + tok0 + r) * (AD_ / 4) + (k0 >> 2) + kq];
            *(float4*)&sA[r][kq * 4] = v;
        }
        for (int idx = tid; idx < 128 * 8; idx += 256) {
            int c = idx >> 3, kq = idx & 7;
            float4 v = ((const float4*)afc_w)[(size_t)c * (AD_ / 4) + (k0 >> 2) + kq];
            *(float4*)&sW[c][kq * 4] = v;
        }
        __syncthreads();
        #pragma unroll 8
        for (int kk = 0; kk < KC; ++kk) {
            float a0 = sA[r0 + 0][kk], a1 = sA[r0 + 1][kk];
            float a2 = sA[r0 + 2][kk], a3 = sA[r0 + 3][kk];
            #pragma unroll
            for (int j = 0; j < 8; ++j) {
                float w = sW[c0 + j][kk];
                acc[0][j] = fmaf(a0, w, acc[0][j]);
                acc[1][j] = fmaf(a1, w, acc[1][j]);
                acc[2][j] = fmaf(a2, w, acc[2][j]);
                acc[3][j] = fmaf(a3, w, acc[3][j]);
            }
        }
        __syncthreads();
    }
    #pragma unroll
    for (int j = 0; j < 8; ++j) {
        float bias = afc_b[c0 + j];
        #pragma unroll
        for (int i = 0; i < 4; ++i)
            sF[r0 + i][c0 + j] = fmaxf(acc[i][j] + bias, 0.0f);
    }
    __syncthreads();

    // ---------------- Phase B: gate = sigmoid(ax @ am_w^T + am_b) ----------------
    #pragma unroll
    for (int i = 0; i < 4; ++i)
        #pragma unroll
        for (int j = 0; j < 8; ++j) acc[i][j] = 0.0f;

    for (int k0 = 0; k0 < SD_; k0 += KC) {
        for (int idx = tid; idx < 128 * 8; idx += 256) {
            int c = idx >> 3, kq = idx & 7;
            float4 v = ((const float4*)am_w)[(size_t)c * (SD_ / 4) + (k0 >> 2) + kq];
            *(float4*)&sW[c][kq * 4] = v;
        }
        __syncthreads();
        #pragma unroll 8
        for (int kk = 0; kk < KC; ++kk) {
            float a0 = sF[r0 + 0][k0 + kk], a1 = sF[r0 + 1][k0 + kk];
            float a2 = sF[r0 + 2][k0 + kk], a3 = sF[r0 + 3][k0 + kk];
            #pragma unroll
            for (int j = 0; j < 8; ++j) {
                float w = sW[c0 + j][kk];
                acc[0][j] = fmaf(a0, w, acc[0][j]);
                acc[1][j] = fmaf(a1, w, acc[1][j]);
                acc[2][j] = fmaf(a2, w, acc[2][j]);
                acc[3][j] = fmaf(a3, w, acc[3][j]);
            }
        }
        __syncthreads();
    }
    #pragma unroll
    for (int j = 0; j < 8; ++j) {
        float bias = am_b[c0 + j];
        #pragma unroll
        for (int i = 0; i < 4; ++i)
            gate[i][j] = sigmoidf_(acc[i][j] + bias);
    }

    // ---------------- Phase C: vo1 = relu(vfeat @ vfc_w^T + vfc_b) ----------------
    #pragma unroll
    for (int i = 0; i < 4; ++i)
        #pragma unroll
        for (int j = 0; j < 8; ++j) acc[i][j] = 0.0f;

    for (int k0 = 0; k0 < VD_; k0 += KC) {
        for (int idx = tid; idx < TM * 8; idx += 256) {
            int r = idx >> 3, kq = idx & 7;
            float4 v = ((const float4*)vfeat)[(size_t)(b * N_ + tok0 + r) * (VD_ / 4) + (k0 >> 2) + kq];
            *(float4*)&sA[r][kq * 4] = v;
        }
        for (int idx = tid; idx < 128 * 8; idx += 256) {
            int c = idx >> 3, kq = idx & 7;
            float4 v = ((const float4*)vfc_w)[(size_t)c * (VD_ / 4) + (k0 >> 2) + kq];
            *(float4*)&sW[c][kq * 4] = v;
        }
        __syncthreads();
        #pragma unroll 8
        for (int kk = 0; kk < KC; ++kk) {
            float a0 = sA[r0 + 0][kk], a1 = sA[r0 + 1][kk];
            float a2 = sA[r0 + 2][kk], a3 = sA[r0 + 3][kk];
            #pragma unroll
            for (int j = 0; j < 8; ++j) {
                float w = sW[c0 + j][kk];
                acc[0][j] = fmaf(a0, w, acc[0][j]);
                acc[1][j] = fmaf(a1, w, acc[1][j]);
                acc[2][j] = fmaf(a2, w, acc[2][j]);
                acc[3][j] = fmaf(a3, w, acc[3][j]);
            }
        }
        __syncthreads();
    }
    // ffeat = vo1 * (1 + gate)  -> sF (overwrites ax; all ax reads done)
    #pragma unroll
    for (int j = 0; j < 8; ++j) {
        float bias = vfc_b[c0 + j];
        #pragma unroll
        for (int i = 0; i < 4; ++i) {
            float vo1 = fmaxf(acc[i][j] + bias, 0.0f);
            sF[r0 + i][c0 + j] = vo1 * (1.0f + gate[i][j]);
        }
    }
    __syncthreads();

    // ---------------- Phase E: v,u heads + score s ----------------
    // cols: tx*4+j (j<4) of v-half and 64+tx*4+j of u-half (paired for v*u)
    float vacc[4][4], uacc[4][4];
    #pragma unroll
    for (int i = 0; i < 4; ++i)
        #pragma unroll
        for (int j = 0; j < 4; ++j) { vacc[i][j] = 0.0f; uacc[i][j] = 0.0f; }

    for (int k0 = 0; k0 < SD_; k0 += KC) {
        for (int idx = tid; idx < 128 * 8; idx += 256) {
            int c = idx >> 3, kq = idx & 7;
            const float* src = (c < 64) ? (V_w + (size_t)c * SD_) : (U_w + (size_t)(c - 64) * SD_);
            float4 v = ((const float4*)src)[(k0 >> 2) + kq];
            *(float4*)&sW[c][kq * 4] = v;
        }
        __syncthreads();
        #pragma unroll 8
        for (int kk = 0; kk < KC; ++kk) {
            float a0 = sF[r0 + 0][k0 + kk], a1 = sF[r0 + 1][k0 + kk];
            float a2 = sF[r0 + 2][k0 + kk], a3 = sF[r0 + 3][k0 + kk];
            #pragma unroll
            for (int j = 0; j < 4; ++j) {
                float wv = sW[tx * 4 + j][kk];
                float wu = sW[64 + tx * 4 + j][kk];
                vacc[0][j] = fmaf(a0, wv, vacc[0][j]);
                vacc[1][j] = fmaf(a1, wv, vacc[1][j]);
                vacc[2][j] = fmaf(a2, wv, vacc[2][j]);
                vacc[3][j] = fmaf(a3, wv, vacc[3][j]);
                uacc[0][j] = fmaf(a0, wu, uacc[0][j]);
                uacc[1][j] = fmaf(a1, wu, uacc[1][j]);
                uacc[2][j] = fmaf(a2, wu, uacc[2][j]);
                uacc[3][j] = fmaf(a3, wu, uacc[3][j]);
            }
        }
        __syncthreads();
    }
    {
        float ww[4], vb[4], ub[4];
        #pragma unroll
        for (int j = 0; j < 4; ++j) {
            ww[j] = W_w[tx * 4 + j];
            vb[j] = V_b[tx * 4 + j];
            ub[j] = U_b[tx * 4 + j];
        }
        float wb = W_b[0];
        #pragma unroll
        for (int i = 0; i < 4; ++i) {
            float p = 0.0f;
            #pragma unroll
            for (int j = 0; j < 4; ++j) {
                float v = fmaxf(vacc[i][j] + vb[j], 0.0f);
                float u = sigmoidf_(uacc[i][j] + ub[j]);
                p = fmaf(v * u, ww[j], p);
            }
            // reduce over the 16 tx lanes (same ty group within the wave)
            p += __shfl_xor(p, 1);
            p += __shfl_xor(p, 2);
            p += __shfl_xor(p, 4);
            p += __shfl_xor(p, 8);
            if (tx == 0) {
                float sv = p + wb;
                s_out[(size_t)b * N_ + tok0 + r0 + i] = sv;
                sS[r0 + i] = sv;
            }
        }
    }
    __syncthreads();

    // ---------------- Phase F: partial z[b][k] = sum_tok s*ffeat ----------------
    if (tid < 128) {
        int k = tid;
        float z = 0.0f;
        #pragma unroll 8
        for (int r = 0; r < TM; ++r) z = fmaf(sS[r], sF[r][k], z);
        zpart[(size_t)bx * 128 + k] = z;   // [b][tile][k]
    }
}

// Grid: 32 blocks (one per b), 128 threads.
__global__ __launch_bounds__(128)
void reduce_logits(const float* __restrict__ zpart,
                   const float* __restrict__ cls_w, const float* __restrict__ cls_b,
                   float* __restrict__ out)
{
    __shared__ float sZ[128];
    int b = blockIdx.x;
    int k = threadIdx.x;
    float z = 0.0f;
    #pragma unroll
    for (int t = 0; t < 32; ++t) z += zpart[(size_t)(b * 32 + t) * 128 + k];
    sZ[k] = z;
    __syncthreads();
    if (k < 2) {
        float acc = cls_b[k];
        for (int i = 0; i < 128; ++i) acc = fmaf(sZ[i], cls_w[k * 128 + i], acc);
        out[(size_t)B_ * N_ + b * 2 + k] = acc;
    }
}

extern "C" void kernel_launch(void* const* d_in, const int* in_sizes, int n_in,
                              void* d_out, int out_size, void* d_ws, size_t ws_size,
                              hipStream_t stream) {
    const float* vfeat = (const float*)d_in[0];
    const float* afeat = (const float*)d_in[1];
    const float* vfc_w = (const float*)d_in[2];
    const float* vfc_b = (const float*)d_in[3];
    const float* afc_w = (const float*)d_in[4];
    const float* afc_b = (const float*)d_in[5];
    const float* am_w  = (const float*)d_in[6];
    const float* am_b  = (const float*)d_in[7];
    const float* U_w   = (const float*)d_in[8];
    const float* U_b   = (const float*)d_in[9];
    const float* V_w   = (const float*)d_in[10];
    const float* V_b   = (const float*)d_in[11];
    const float* W_w   = (const float*)d_in[12];
    const float* W_b   = (const float*)d_in[13];
    const float* cls_w = (const float*)d_in[14];
    const float* cls_b = (const float*)d_in[15];

    float* out   = (float*)d_out;
    float* zpart = (float*)d_ws;   // 1024*128*4 = 512 KB

    fused_mil<<<dim3(B_ * 32), dim3(256), 0, stream>>>(
        vfeat, afeat, vfc_w, vfc_b, afc_w, afc_b, am_w, am_b,
        U_w, U_b, V_w, V_b, W_w, W_b, out, zpart);
    reduce_logits<<<dim3(B_), dim3(128), 0, stream>>>(zpart, cls_w, cls_b, out);
}

// Round 2
// 60.344 us; speedup vs baseline: 7.8761x; 7.8761x over previous
//
#include <hip/hip_runtime.h>
#include <hip/hip_bf16.h>

#define B_   32
#define N_   2048
#define VD_  512
#define AD_  128
#define SD_  128
#define TM   128      // tokens per block
#define THREADS 512   // 8 waves: wr = wid>>1 (row tile of 32), wc = wid&1 (col half of 64)

typedef __attribute__((ext_vector_type(8))) short short8;
typedef __attribute__((ext_vector_type(4))) float f32x4;

__device__ __forceinline__ float sigmoidf_(float x) { return 1.0f / (1.0f + __expf(-x)); }

// f32 -> bf16 RNE (inputs finite; no NaN handling needed)
__device__ __forceinline__ ushort f2bf(float x) {
    union { float f; unsigned int i; } v; v.f = x;
    unsigned int r = v.i + 0x7FFFu + ((v.i >> 16) & 1u);
    return (ushort)(r >> 16);
}
__device__ __forceinline__ float bf2f(ushort u) {
    union { unsigned int i; float f; } v; v.i = ((unsigned int)u) << 16; return v.f;
}

// Swizzled element index into row-major [R][ldk] ushort LDS tile.
// byte ^= ((row&7)<<4)  ==  elem ^= ((row&7)<<3). Keeps 8-elem (16B) chunks intact.
__device__ __forceinline__ int swz(int row, int k, int ldk) {
    return row * ldk + (k ^ ((row & 7) << 3));
}

// One K=64 chunk of a block GEMM. A-operand rows = tokens (from Ab, leading dim ldkA,
// k offset kA0); B-operand cols = weights staged in Wb[128][64]. Wave (wr,wc) owns a
// 32x64 output tile: mrep=2 (rows +0/+16), nrep=4 (cols 16*n). Fragment layout:
// lane holds row/col (lane&15), k = (lane>>4)*8 + 0..7 (contiguous-8, per m92/m97).
__device__ __forceinline__ void gemm_chunk(const ushort* Ab, int ldkA, int kA0,
                                           const ushort* Wb,
                                           int wr, int wc, int t16, int g4,
                                           f32x4 (&acc)[2][4])
{
    #pragma unroll
    for (int kk = 0; kk < 2; ++kk) {
        const int k = kk * 32 + g4 * 8;
        short8 a0 = *(const short8*)&Ab[swz(32 * wr + t16,      kA0 + k, ldkA)];
        short8 a1 = *(const short8*)&Ab[swz(32 * wr + 16 + t16, kA0 + k, ldkA)];
        #pragma unroll
        for (int n = 0; n < 4; ++n) {
            short8 bf = *(const short8*)&Wb[swz(64 * wc + 16 * n + t16, k, 64)];
            acc[0][n] = __builtin_amdgcn_mfma_f32_16x16x32_bf16(a0, bf, acc[0][n], 0, 0, 0);
            acc[1][n] = __builtin_amdgcn_mfma_f32_16x16x32_bf16(a1, bf, acc[1][n], 0, 0, 0);
        }
    }
}

// Grid: 32 b x 16 tiles = 512 blocks, 512 threads.
__global__ __launch_bounds__(THREADS, 1)
void fused_mil(const float* __restrict__ vfeat, const float* __restrict__ afeat,
               const float* __restrict__ vfc_w, const float* __restrict__ vfc_b,
               const float* __restrict__ afc_w, const float* __restrict__ afc_b,
               const float* __restrict__ am_w,  const float* __restrict__ am_b,
               const float* __restrict__ U_w,   const float* __restrict__ U_b,
               const float* __restrict__ V_w,   const float* __restrict__ V_b,
               const float* __restrict__ W_w,   const float* __restrict__ W_b,
               float* __restrict__ s_out, float* __restrict__ zpart)
{
    __shared__ __align__(16) ushort Xbuf[128 * 128]; // afeat-bf16, later ffeat
    __shared__ __align__(16) ushort Axb [128 * 128]; // ax
    __shared__ __align__(16) ushort Wb  [128 * 64];  // weight chunk [col][64]
    __shared__ __align__(16) ushort Cb  [128 * 64];  // vfeat chunk  [row][64]
    __shared__ float sP[2][128];
    __shared__ float sS[128];
    __shared__ float zq[4][128];

    const int tid  = threadIdx.x;
    const int bx   = blockIdx.x;
    const int b    = bx >> 4;
    const int tok0 = (bx & 15) * TM;
    const int wid  = tid >> 6;
    const int lane = tid & 63;
    const int t16  = lane & 15;
    const int g4   = lane >> 4;
    const int wr   = wid >> 1;
    const int wc   = wid & 1;

    f32x4 acc[2][4], gacc[2][4];

    // ---- stage afeat [128][128] f32 -> bf16 Xbuf (swizzled) ----
    {
        const float4* src = (const float4*)(afeat + ((size_t)b * N_ + tok0) * AD_);
        #pragma unroll
        for (int i = 0; i < 8; ++i) {
            int fid = tid + i * THREADS;          // 4096 float4s
            int r = fid >> 5, kq = fid & 31;
            float4 v = src[r * 32 + kq];
            ushort4 o; o.x = f2bf(v.x); o.y = f2bf(v.y); o.z = f2bf(v.z); o.w = f2bf(v.w);
            *(ushort4*)&Xbuf[swz(r, kq * 4, 128)] = o;
        }
    }

    // ---- Phase A: ax = relu(afeat @ afc_w^T + afc_b) ----
    #pragma unroll
    for (int m = 0; m < 2; ++m)
        #pragma unroll
        for (int n = 0; n < 4; ++n) acc[m][n] = (f32x4)0.0f;

    for (int kc = 0; kc < AD_; kc += 64) {
        #pragma unroll
        for (int i = 0; i < 4; ++i) {           // stage afc_w chunk [128][64]
            int fid = tid + i * THREADS;
            int c = fid >> 4, kq = fid & 15;
            float4 v = ((const float4*)afc_w)[c * 32 + (kc >> 2) + kq];
            ushort4 o; o.x = f2bf(v.x); o.y = f2bf(v.y); o.z = f2bf(v.z); o.w = f2bf(v.w);
            *(ushort4*)&Wb[swz(c, kq * 4, 64)] = o;
        }
        __syncthreads();
        gemm_chunk(Xbuf, 128, kc, Wb, wr, wc, t16, g4, acc);
        __syncthreads();
    }
    #pragma unroll
    for (int n = 0; n < 4; ++n) {
        int c = 64 * wc + 16 * n + t16;
        float bias = afc_b[c];
        #pragma unroll
        for (int m = 0; m < 2; ++m)
            #pragma unroll
            for (int r = 0; r < 4; ++r) {
                int row = 32 * wr + 16 * m + 4 * g4 + r;
                Axb[swz(row, c, 128)] = f2bf(fmaxf(acc[m][n][r] + bias, 0.0f));
            }
    }

    // ---- Phase B: gate_acc = ax @ am_w^T (kept in regs) ----
    #pragma unroll
    for (int m = 0; m < 2; ++m)
        #pragma unroll
        for (int n = 0; n < 4; ++n) gacc[m][n] = (f32x4)0.0f;

    for (int kc = 0; kc < SD_; kc += 64) {
        #pragma unroll
        for (int i = 0; i < 4; ++i) {           // stage am_w chunk
            int fid = tid + i * THREADS;
            int c = fid >> 4, kq = fid & 15;
            float4 v = ((const float4*)am_w)[c * 32 + (kc >> 2) + kq];
            ushort4 o; o.x = f2bf(v.x); o.y = f2bf(v.y); o.z = f2bf(v.z); o.w = f2bf(v.w);
            *(ushort4*)&Wb[swz(c, kq * 4, 64)] = o;
        }
        __syncthreads();   // also orders Axb writes before reads
        gemm_chunk(Axb, 128, kc, Wb, wr, wc, t16, g4, gacc);
        __syncthreads();
    }

    // ---- Phase C: vo1 = vfeat @ vfc_w^T, K=512 in 8 chunks, reg-prefetch (T14) ----
    #pragma unroll
    for (int m = 0; m < 2; ++m)
        #pragma unroll
        for (int n = 0; n < 4; ++n) acc[m][n] = (f32x4)0.0f;

    {
        const float4* vsrc = (const float4*)(vfeat + ((size_t)b * N_ + tok0) * VD_); // ld 128
        const float4* wsrc = (const float4*)vfc_w;                                   // ld 128
        float4 pv[4], pw[4];
        #pragma unroll
        for (int i = 0; i < 4; ++i) {
            int fid = tid + i * THREADS;
            int r = fid >> 4, kq = fid & 15;
            pv[i] = vsrc[r * 128 + kq];
            pw[i] = wsrc[r * 128 + kq];
        }
        for (int c = 0; c < 8; ++c) {
            #pragma unroll
            for (int i = 0; i < 4; ++i) {       // write prefetched chunk to LDS
                int fid = tid + i * THREADS;
                int r = fid >> 4, kq = fid & 15;
                ushort4 ov; ov.x = f2bf(pv[i].x); ov.y = f2bf(pv[i].y); ov.z = f2bf(pv[i].z); ov.w = f2bf(pv[i].w);
                *(ushort4*)&Cb[swz(r, kq * 4, 64)] = ov;
                ushort4 ow; ow.x = f2bf(pw[i].x); ow.y = f2bf(pw[i].y); ow.z = f2bf(pw[i].z); ow.w = f2bf(pw[i].w);
                *(ushort4*)&Wb[swz(r, kq * 4, 64)] = ow;
            }
            __syncthreads();
            if (c < 7) {                        // issue next-chunk loads; fly under MFMA
                int kq0 = (c + 1) * 16;
                #pragma unroll
                for (int i = 0; i < 4; ++i) {
                    int fid = tid + i * THREADS;
                    int r = fid >> 4, kq = fid & 15;
                    pv[i] = vsrc[r * 128 + kq0 + kq];
                    pw[i] = wsrc[r * 128 + kq0 + kq];
                }
            }
            gemm_chunk(Cb, 64, 0, Wb, wr, wc, t16, g4, acc);
            __syncthreads();
        }
    }

    // ---- Epilogue C: ffeat = relu(vo1+b) * (1 + sigmoid(gate+b)) -> Xbuf (bf16) ----
    #pragma unroll
    for (int n = 0; n < 4; ++n) {
        int c = 64 * wc + 16 * n + t16;
        float vb = vfc_b[c], ab = am_b[c];
        #pragma unroll
        for (int m = 0; m < 2; ++m)
            #pragma unroll
            for (int r = 0; r < 4; ++r) {
                int row = 32 * wr + 16 * m + 4 * g4 + r;
                float vo1 = fmaxf(acc[m][n][r] + vb, 0.0f);
                float g   = sigmoidf_(gacc[m][n][r] + ab);
                Xbuf[swz(row, c, 128)] = f2bf(vo1 * (1.0f + g));
            }
    }

    // ---- Phase E: [V | U] heads. Weight cols interleaved per 32 so wave wc pairs
    //      v (n=0,1) with u (n=2,3) at the same h = 32*wc + 16*(n&1) + t16 ----
    #pragma unroll
    for (int m = 0; m < 2; ++m)
        #pragma unroll
        for (int n = 0; n < 4; ++n) acc[m][n] = (f32x4)0.0f;

    for (int kc = 0; kc < SD_; kc += 64) {
        #pragma unroll
        for (int i = 0; i < 4; ++i) {
            int fid = tid + i * THREADS;
            int cc = fid >> 4, kq = fid & 15;
            int g = cc >> 5, q = cc & 31;
            int h = 32 * (g >> 1) + q;
            const float* srcrow = (g & 1) ? (U_w + (size_t)h * SD_) : (V_w + (size_t)h * SD_);
            float4 v = ((const float4*)srcrow)[(kc >> 2) + kq];
            ushort4 o; o.x = f2bf(v.x); o.y = f2bf(v.y); o.z = f2bf(v.z); o.w = f2bf(v.w);
            *(ushort4*)&Wb[swz(cc, kq * 4, 64)] = o;
        }
        __syncthreads();   // also orders Xbuf(ffeat) writes before reads
        gemm_chunk(Xbuf, 128, kc, Wb, wr, wc, t16, g4, acc);
        __syncthreads();
    }

    // ---- score s = sum_h relu(v)*sigmoid(u)*W_w + W_b ----
    #pragma unroll
    for (int m = 0; m < 2; ++m)
        #pragma unroll
        for (int r = 0; r < 4; ++r) {
            float p = 0.0f;
            #pragma unroll
            for (int n = 0; n < 2; ++n) {
                int h = 32 * wc + 16 * n + t16;
                float vv = fmaxf(acc[m][n][r] + V_b[h], 0.0f);
                float uu = sigmoidf_(acc[m][n + 2][r] + U_b[h]);
                p = fmaf(vv * uu, W_w[h], p);
            }
            p += __shfl_xor(p, 1);
            p += __shfl_xor(p, 2);
            p += __shfl_xor(p, 4);
            p += __shfl_xor(p, 8);
            if (t16 == 0) sP[wc][32 * wr + 16 * m + 4 * g4 + r] = p;
        }
    __syncthreads();
    if (tid < 128) {
        float s = sP[0][tid] + sP[1][tid] + W_b[0];
        sS[tid] = s;
        s_out[(size_t)b * N_ + tok0 + tid] = s;
    }
    __syncthreads();

    // ---- Phase F: zpart[k] = sum_t s[t] * ffeat[t][k] ----
    {
        int k = tid & 127, q = tid >> 7;
        float z = 0.0f;
        #pragma unroll
        for (int t = 0; t < 32; ++t) {
            int row = q * 32 + t;
            z = fmaf(sS[row], bf2f(Xbuf[swz(row, k, 128)]), z);
        }
        zq[q][k] = z;
    }
    __syncthreads();
    if (tid < 128)
        zpart[(size_t)bx * 128 + tid] = zq[0][tid] + zq[1][tid] + zq[2][tid] + zq[3][tid];
}

// Grid: 32 blocks, 128 threads.
__global__ __launch_bounds__(128)
void reduce_logits(const float* __restrict__ zpart,
                   const float* __restrict__ cls_w, const float* __restrict__ cls_b,
                   float* __restrict__ out)
{
    __shared__ float sZ[128];
    int b = blockIdx.x, k = threadIdx.x;
    float z = 0.0f;
    #pragma unroll
    for (int t = 0; t < 16; ++t) z += zpart[(size_t)(b * 16 + t) * 128 + k];
    sZ[k] = z;
    __syncthreads();
    if (k < 2) {
        float acc = cls_b[k];
        for (int i = 0; i < 128; ++i) acc = fmaf(sZ[i], cls_w[k * 128 + i], acc);
        out[(size_t)B_ * N_ + b * 2 + k] = acc;
    }
}

extern "C" void kernel_launch(void* const* d_in, const int* in_sizes, int n_in,
                              void* d_out, int out_size, void* d_ws, size_t ws_size,
                              hipStream_t stream) {
    const float* vfeat = (const float*)d_in[0];
    const float* afeat = (const float*)d_in[1];
    const float* vfc_w = (const float*)d_in[2];
    const float* vfc_b = (const float*)d_in[3];
    const float* afc_w = (const float*)d_in[4];
    const float* afc_b = (const float*)d_in[5];
    const float* am_w  = (const float*)d_in[6];
    const float* am_b  = (const float*)d_in[7];
    const float* U_w   = (const float*)d_in[8];
    const float* U_b   = (const float*)d_in[9];
    const float* V_w   = (const float*)d_in[10];
    const float* V_b   = (const float*)d_in[11];
    const float* W_w   = (const float*)d_in[12];
    const float* W_b   = (const float*)d_in[13];
    const float* cls_w = (const float*)d_in[14];
    const float* cls_b = (const float*)d_in[15];

    float* out   = (float*)d_out;
    float* zpart = (float*)d_ws;   // 512*128*4 = 256 KB

    fused_mil<<<dim3(B_ * 16), dim3(THREADS), 0, stream>>>(
        vfeat, afeat, vfc_w, vfc_b, afc_w, afc_b, am_w, am_b,
        U_w, U_b, V_w, V_b, W_w, W_b, out, zpart);
    reduce_logits<<<dim3(B_), dim3(128), 0, stream>>>(zpart, cls_w, cls_b, out);
}